// Round 1
// baseline (610.622 us; speedup 1.0000x reference)
//
#include <hip/hip_runtime.h>
#include <hip/hip_bf16.h>
#include <math.h>

#define B_ 256
#define S_ 512
#define H_ 256
#define D_ 512

typedef __bf16 bf16;
typedef __bf16 bf16x8 __attribute__((ext_vector_type(8)));
typedef float  f32x4  __attribute__((ext_vector_type(4)));
typedef unsigned short u16x8 __attribute__((ext_vector_type(8)));
typedef unsigned short u16x4 __attribute__((ext_vector_type(4)));

#define MFMA(a, b, c) __builtin_amdgcn_mfma_f32_16x16x32_bf16((a), (b), (c), 0, 0, 0)

// LDS tiles are [rows][64 k] bf16, row stride 128B. XOR-swizzle byte 4..6 with
// row&7 so ds_read_b128 down 16 rows at fixed k hits 8 distinct 16B slots
// (2-way alias = free). Same involution on write and read (rule #21).
__device__ __forceinline__ int swz(int row, int kbyte) {
  return (row * 128 + kbyte) ^ ((row & 7) << 4);
}
__device__ __forceinline__ unsigned short bfbits(float f) {
  bf16 h = (bf16)f;
  union { bf16 b; unsigned short u; } c; c.b = h; return c.u;
}
__device__ __forceinline__ bf16x8 cvt8(const float* __restrict__ p) {
  f32x4 a = *(const f32x4*)p;
  f32x4 b = *(const f32x4*)(p + 4);
  bf16x8 r;
  r[0] = (bf16)a[0]; r[1] = (bf16)a[1]; r[2] = (bf16)a[2]; r[3] = (bf16)a[3];
  r[4] = (bf16)b[0]; r[5] = (bf16)b[1]; r[6] = (bf16)b[2]; r[7] = (bf16)b[3];
  return r;
}

// ---------------------------------------------------------------------------
// Kernel 1: fused QKV projection. C[m,n] = x[m,:]·W[n,:] + b[n].
// Grid (6 n-tiles, 1024 m-tiles), n fastest so the x tile is L2/L3-hot across
// the 6 column tiles. Regions: n<256 -> k (store transposed k_t[b][h][s]),
// 256..511 -> q (q_t[b][h][s]), 512..767 -> v (v[b][s][h]).
// ---------------------------------------------------------------------------
__global__ __launch_bounds__(512) void k_proj(
    const float* __restrict__ x,
    const float* __restrict__ kw, const float* __restrict__ kb,
    const float* __restrict__ qw, const float* __restrict__ qb,
    const float* __restrict__ vw, const float* __restrict__ vb,
    unsigned short* __restrict__ k_t, unsigned short* __restrict__ q_t,
    unsigned short* __restrict__ v_o)
{
  __shared__ __align__(16) unsigned char sA[128 * 128];  // 128 x 64 bf16
  __shared__ __align__(16) unsigned char sB[128 * 128];

  const int tid = threadIdx.x;
  const int lane = tid & 63;
  const int wid = tid >> 6;
  const int wm = wid >> 2;              // 0..1  -> 64 m rows
  const int wn = wid & 3;               // 0..3  -> 32 n cols
  const int m0 = blockIdx.y * 128;
  const int nb = blockIdx.x;            // 0..5
  const int region = nb >> 1;           // 0=k 1=q 2=v
  const int h0 = (nb & 1) * 128;
  const float* __restrict__ W  = (region == 0) ? kw : (region == 1) ? qw : vw;
  const float* __restrict__ Bi = (region == 0) ? kb : (region == 1) ? qb : vb;

  f32x4 acc[4][2];
#pragma unroll
  for (int i = 0; i < 4; ++i)
#pragma unroll
    for (int j = 0; j < 2; ++j) acc[i][j] = (f32x4){0.f, 0.f, 0.f, 0.f};

  for (int kt = 0; kt < 8; ++kt) {
    __syncthreads();
#pragma unroll
    for (int i = 0; i < 2; ++i) {                       // x tile: 1024 chunks
      int c = tid + i * 512;
      int row = c >> 3, kc = (c & 7) * 8;
      *(bf16x8*)(sA + swz(row, kc * 2)) =
          cvt8(x + (size_t)(m0 + row) * D_ + kt * 64 + kc);
    }
#pragma unroll
    for (int i = 0; i < 2; ++i) {                       // W tile
      int c = tid + i * 512;
      int row = c >> 3, kc = (c & 7) * 8;
      *(bf16x8*)(sB + swz(row, kc * 2)) =
          cvt8(W + (size_t)(h0 + row) * D_ + kt * 64 + kc);
    }
    __syncthreads();
#pragma unroll
    for (int ks = 0; ks < 2; ++ks) {
      const int kbyte = ks * 64 + (lane >> 4) * 16;
      bf16x8 av[4], bv[2];
#pragma unroll
      for (int f = 0; f < 4; ++f)
        av[f] = *(const bf16x8*)(sA + swz(wm * 64 + f * 16 + (lane & 15), kbyte));
#pragma unroll
      for (int f = 0; f < 2; ++f)
        bv[f] = *(const bf16x8*)(sB + swz(wn * 32 + f * 16 + (lane & 15), kbyte));
#pragma unroll
      for (int fm = 0; fm < 4; ++fm)
#pragma unroll
        for (int fn = 0; fn < 2; ++fn)
          acc[fm][fn] = MFMA(av[fm], bv[fn], acc[fm][fn]);
    }
  }

  // Epilogue. C frag: col = lane&15 (h), rows = (lane>>4)*4 + j (s within tile).
  const int b = m0 >> 9;                 // 128-row tile sits in one batch
  const int r4 = (lane >> 4) * 4;
#pragma unroll
  for (int fn = 0; fn < 2; ++fn) {
    const int hcol = h0 + wn * 32 + fn * 16 + (lane & 15);
    const float bias = Bi[hcol];
#pragma unroll
    for (int fm = 0; fm < 4; ++fm) {
      const int s = (m0 & 511) + wm * 64 + fm * 16 + r4;
      if (region < 2) {
        unsigned short* dst = ((region == 0) ? k_t : q_t) +
                              (size_t)b * (H_ * S_) + (size_t)hcol * S_ + s;
        u16x4 o;
#pragma unroll
        for (int j = 0; j < 4; ++j) o[j] = bfbits(acc[fm][fn][j] + bias);
        *(u16x4*)dst = o;                                 // 4 consecutive s
      } else {
#pragma unroll
        for (int j = 0; j < 4; ++j)
          v_o[(size_t)b * (S_ * H_) + (size_t)(s + j) * H_ + hcol] =
              bfbits(acc[fm][fn][j] + bias);
      }
    }
  }
}

// ---------------------------------------------------------------------------
// Kernel 2: scores + column softmax. Per (b, 64-g block):
// S[h,g] = (1/16) * sum_s k_t[b][h][s] * q_t[b][g][s]; softmax over h;
// write w_t[b][g][h] bf16 (the [N][K] layout PV wants).
// ---------------------------------------------------------------------------
__global__ __launch_bounds__(512) void k_scores(
    const unsigned short* __restrict__ k_t,
    const unsigned short* __restrict__ q_t,
    unsigned short* __restrict__ w_t)
{
  __shared__ __align__(16) unsigned char sA[256 * 128];  // 256 h x 64 s, 32KB
  __shared__ __align__(16) unsigned char sB[64 * 128];   // 64 g x 64 s, 8KB
  __shared__ float red[4][64];

  const int tid = threadIdx.x;
  const int lane = tid & 63;
  const int wid = tid >> 6;
  const int wm = wid >> 1;              // 0..3 -> 64 h rows
  const int wn = wid & 1;               // 0..1 -> 32 g cols
  const int b = blockIdx.y;
  const int g0 = blockIdx.x * 64;

  const unsigned short* __restrict__ Ab = k_t + (size_t)b * (H_ * S_);
  const unsigned short* __restrict__ Bb = q_t + (size_t)b * (H_ * S_) + (size_t)g0 * S_;

  f32x4 acc[4][2];
#pragma unroll
  for (int i = 0; i < 4; ++i)
#pragma unroll
    for (int j = 0; j < 2; ++j) acc[i][j] = (f32x4){0.f, 0.f, 0.f, 0.f};

  for (int kt = 0; kt < 8; ++kt) {
    __syncthreads();
#pragma unroll
    for (int i = 0; i < 4; ++i) {                        // A: 2048 chunks
      int c = tid + i * 512;
      int row = c >> 3, kc = (c & 7) * 8;
      *(u16x8*)(sA + swz(row, kc * 2)) =
          *(const u16x8*)(Ab + (size_t)row * S_ + kt * 64 + kc);
    }
    {                                                    // B: 512 chunks
      int row = tid >> 3, kc = (tid & 7) * 8;
      *(u16x8*)(sB + swz(row, kc * 2)) =
          *(const u16x8*)(Bb + (size_t)row * S_ + kt * 64 + kc);
    }
    __syncthreads();
#pragma unroll
    for (int ks = 0; ks < 2; ++ks) {
      const int kbyte = ks * 64 + (lane >> 4) * 16;
      bf16x8 av[4], bv[2];
#pragma unroll
      for (int f = 0; f < 4; ++f)
        av[f] = *(const bf16x8*)(sA + swz(wm * 64 + f * 16 + (lane & 15), kbyte));
#pragma unroll
      for (int f = 0; f < 2; ++f)
        bv[f] = *(const bf16x8*)(sB + swz(wn * 32 + f * 16 + (lane & 15), kbyte));
#pragma unroll
      for (int fm = 0; fm < 4; ++fm)
#pragma unroll
        for (int fn = 0; fn < 2; ++fn)
          acc[fm][fn] = MFMA(av[fm], bv[fn], acc[fm][fn]);
    }
  }

  // scale 256^-0.5 = 1/16
#pragma unroll
  for (int fm = 0; fm < 4; ++fm)
#pragma unroll
    for (int fn = 0; fn < 2; ++fn)
#pragma unroll
      for (int j = 0; j < 4; ++j) acc[fm][fn][j] *= 0.0625f;

  // column softmax over 256 h. Lane's column: wn*32 + fn*16 + (lane&15).
  float cmax[2] = {-3.0e38f, -3.0e38f};
#pragma unroll
  for (int fm = 0; fm < 4; ++fm)
#pragma unroll
    for (int fn = 0; fn < 2; ++fn)
#pragma unroll
      for (int j = 0; j < 4; ++j) cmax[fn] = fmaxf(cmax[fn], acc[fm][fn][j]);
  cmax[0] = fmaxf(cmax[0], __shfl_xor(cmax[0], 16));
  cmax[1] = fmaxf(cmax[1], __shfl_xor(cmax[1], 16));
  cmax[0] = fmaxf(cmax[0], __shfl_xor(cmax[0], 32));
  cmax[1] = fmaxf(cmax[1], __shfl_xor(cmax[1], 32));
  if (lane < 16) {
    red[wm][wn * 32 + lane] = cmax[0];
    red[wm][wn * 32 + 16 + lane] = cmax[1];
  }
  __syncthreads();
  float gmax[2];
#pragma unroll
  for (int fn = 0; fn < 2; ++fn) {
    int c = wn * 32 + fn * 16 + (lane & 15);
    gmax[fn] = fmaxf(fmaxf(red[0][c], red[1][c]), fmaxf(red[2][c], red[3][c]));
  }
  __syncthreads();
  float csum[2] = {0.f, 0.f};
#pragma unroll
  for (int fm = 0; fm < 4; ++fm)
#pragma unroll
    for (int fn = 0; fn < 2; ++fn)
#pragma unroll
      for (int j = 0; j < 4; ++j) {
        float p = __expf(acc[fm][fn][j] - gmax[fn]);
        acc[fm][fn][j] = p;
        csum[fn] += p;
      }
  csum[0] += __shfl_xor(csum[0], 16);
  csum[1] += __shfl_xor(csum[1], 16);
  csum[0] += __shfl_xor(csum[0], 32);
  csum[1] += __shfl_xor(csum[1], 32);
  if (lane < 16) {
    red[wm][wn * 32 + lane] = csum[0];
    red[wm][wn * 32 + 16 + lane] = csum[1];
  }
  __syncthreads();
  const int r4 = (lane >> 4) * 4;
#pragma unroll
  for (int fn = 0; fn < 2; ++fn) {
    int c = wn * 32 + fn * 16 + (lane & 15);
    float ginv = 1.0f / (red[0][c] + red[1][c] + red[2][c] + red[3][c]);
    int g = g0 + c;
#pragma unroll
    for (int fm = 0; fm < 4; ++fm) {
      int h = wm * 64 + fm * 16 + r4;
      u16x4 o;
#pragma unroll
      for (int j = 0; j < 4; ++j) o[j] = bfbits(acc[fm][fn][j] * ginv);
      *(u16x4*)(w_t + (size_t)b * (H_ * H_) + (size_t)g * H_ + h) = o;
    }
  }
}

// ---------------------------------------------------------------------------
// Kernel 3: out = v·w + attn_bias, LayerNorm over g (N=256 = full row in WG),
// exact-erf GELU, store act bf16 [b][s][g].
// ---------------------------------------------------------------------------
__global__ __launch_bounds__(512) void k_pv(
    const unsigned short* __restrict__ v_o,
    const unsigned short* __restrict__ w_t,
    const float* __restrict__ attn_bias,
    const float* __restrict__ lng,
    const float* __restrict__ lnb,
    unsigned short* __restrict__ act)
{
  __shared__ __align__(16) unsigned char sA[128 * 128];  // 128 s x 64 h, 16KB
  __shared__ __align__(16) unsigned char sB[256 * 128];  // 256 g x 64 h, 32KB
  __shared__ float lbuf[2][4][128];                      // {sum,sq}[wn][row]

  const int tid = threadIdx.x;
  const int lane = tid & 63;
  const int wid = tid >> 6;
  const int wm = wid >> 2;              // 0..1 -> 64 s rows
  const int wn = wid & 3;               // 0..3 -> 64 g cols
  const int b = blockIdx.y;
  const int s0 = blockIdx.x * 128;

  const unsigned short* __restrict__ Ab = v_o + (size_t)b * (S_ * H_) + (size_t)s0 * H_;
  const unsigned short* __restrict__ Bb = w_t + (size_t)b * (H_ * H_);

  f32x4 acc[4][4];
#pragma unroll
  for (int i = 0; i < 4; ++i)
#pragma unroll
    for (int j = 0; j < 4; ++j) acc[i][j] = (f32x4){0.f, 0.f, 0.f, 0.f};

  for (int kt = 0; kt < 4; ++kt) {
    __syncthreads();
#pragma unroll
    for (int i = 0; i < 2; ++i) {                        // A: 1024 chunks
      int c = tid + i * 512;
      int row = c >> 3, kc = (c & 7) * 8;
      *(u16x8*)(sA + swz(row, kc * 2)) =
          *(const u16x8*)(Ab + (size_t)row * H_ + kt * 64 + kc);
    }
#pragma unroll
    for (int i = 0; i < 4; ++i) {                        // B: 2048 chunks
      int c = tid + i * 512;
      int row = c >> 3, kc = (c & 7) * 8;
      *(u16x8*)(sB + swz(row, kc * 2)) =
          *(const u16x8*)(Bb + (size_t)row * H_ + kt * 64 + kc);
    }
    __syncthreads();
#pragma unroll
    for (int ks = 0; ks < 2; ++ks) {
      const int kbyte = ks * 64 + (lane >> 4) * 16;
      bf16x8 av[4], bv[4];
#pragma unroll
      for (int f = 0; f < 4; ++f)
        av[f] = *(const bf16x8*)(sA + swz(wm * 64 + f * 16 + (lane & 15), kbyte));
#pragma unroll
      for (int f = 0; f < 4; ++f)
        bv[f] = *(const bf16x8*)(sB + swz(wn * 64 + f * 16 + (lane & 15), kbyte));
#pragma unroll
      for (int fm = 0; fm < 4; ++fm)
#pragma unroll
        for (int fn = 0; fn < 4; ++fn)
          acc[fm][fn] = MFMA(av[fm], bv[fn], acc[fm][fn]);
    }
  }

  const int r4 = (lane >> 4) * 4;
  float lg[4], lb[4];
#pragma unroll
  for (int fn = 0; fn < 4; ++fn) {
    int g = wn * 64 + fn * 16 + (lane & 15);
    lg[fn] = lng[g];
    lb[fn] = lnb[g];
  }
  // + attn_bias, per-row partial sums -> LDS
#pragma unroll
  for (int fm = 0; fm < 4; ++fm) {
#pragma unroll
    for (int j = 0; j < 4; ++j) {
      const int rloc = wm * 64 + fm * 16 + r4 + j;
      const int sl = s0 + rloc;
      float ps = 0.f, psq = 0.f;
#pragma unroll
      for (int fn = 0; fn < 4; ++fn) {
        int g = wn * 64 + fn * 16 + (lane & 15);
        float vv = acc[fm][fn][j] + attn_bias[(size_t)sl * H_ + g];
        acc[fm][fn][j] = vv;
        ps += vv;
        psq += vv * vv;
      }
      ps += __shfl_xor(ps, 1);  psq += __shfl_xor(psq, 1);
      ps += __shfl_xor(ps, 2);  psq += __shfl_xor(psq, 2);
      ps += __shfl_xor(ps, 4);  psq += __shfl_xor(psq, 4);
      ps += __shfl_xor(ps, 8);  psq += __shfl_xor(psq, 8);
      if ((lane & 15) == 0) { lbuf[0][wn][rloc] = ps; lbuf[1][wn][rloc] = psq; }
    }
  }
  __syncthreads();
#pragma unroll
  for (int fm = 0; fm < 4; ++fm) {
#pragma unroll
    for (int j = 0; j < 4; ++j) {
      const int rloc = wm * 64 + fm * 16 + r4 + j;
      float sum = lbuf[0][0][rloc] + lbuf[0][1][rloc] + lbuf[0][2][rloc] + lbuf[0][3][rloc];
      float sq  = lbuf[1][0][rloc] + lbuf[1][1][rloc] + lbuf[1][2][rloc] + lbuf[1][3][rloc];
      float mu = sum * (1.f / H_);
      float var = sq * (1.f / H_) - mu * mu;
      float rstd = rsqrtf(var + 1e-5f);
      const int sl = s0 + rloc;
#pragma unroll
      for (int fn = 0; fn < 4; ++fn) {
        int g = wn * 64 + fn * 16 + (lane & 15);
        float xv = (acc[fm][fn][j] - mu) * rstd * lg[fn] + lb[fn];
        float y = 0.5f * xv * (1.f + erff(xv * 0.70710678118654752f));
        act[(size_t)b * (S_ * H_) + (size_t)sl * H_ + g] = bfbits(y);
      }
    }
  }
}

// ---------------------------------------------------------------------------
// Kernel 4: final GEMM, split-K. out[m,n] = sum_k act[m,k]*out_w[n,k].
// Grid (8 n-blocks x 32 k-splits); partials to ws (deterministic, no atomics).
// ---------------------------------------------------------------------------
__global__ __launch_bounds__(512) void k_final(
    const unsigned short* __restrict__ act,
    const float* __restrict__ ow,
    float* __restrict__ partial)
{
  __shared__ __align__(16) unsigned char sA[256 * 128];  // 256 m x 64 k, 32KB
  __shared__ __align__(16) unsigned char sB[64 * 128];   // 64 n x 64 k, 8KB

  const int tid = threadIdx.x;
  const int lane = tid & 63;
  const int wid = tid >> 6;
  const int wm = wid >> 1;              // 0..3 -> 64 m rows
  const int wn = wid & 1;               // 0..1 -> 32 n cols
  const int n0 = blockIdx.x * 64;
  const size_t k0 = (size_t)blockIdx.y * 4096;

  f32x4 acc[4][2];
#pragma unroll
  for (int i = 0; i < 4; ++i)
#pragma unroll
    for (int j = 0; j < 2; ++j) acc[i][j] = (f32x4){0.f, 0.f, 0.f, 0.f};

  for (int kt = 0; kt < 64; ++kt) {
    const size_t kb = k0 + kt * 64;
    __syncthreads();
#pragma unroll
    for (int i = 0; i < 4; ++i) {                        // act: 2048 chunks
      int c = tid + i * 512;
      int row = c >> 3, kc = (c & 7) * 8;
      *(u16x8*)(sA + swz(row, kc * 2)) =
          *(const u16x8*)(act + (size_t)row * 131072 + kb + kc);
    }
    {                                                    // out_w: 512 chunks
      int row = tid >> 3, kc = (tid & 7) * 8;
      *(bf16x8*)(sB + swz(row, kc * 2)) =
          cvt8(ow + (size_t)(n0 + row) * 131072 + kb + kc);
    }
    __syncthreads();
#pragma unroll
    for (int ks = 0; ks < 2; ++ks) {
      const int kbyte = ks * 64 + (lane >> 4) * 16;
      bf16x8 av[4], bv[2];
#pragma unroll
      for (int f = 0; f < 4; ++f)
        av[f] = *(const bf16x8*)(sA + swz(wm * 64 + f * 16 + (lane & 15), kbyte));
#pragma unroll
      for (int f = 0; f < 2; ++f)
        bv[f] = *(const bf16x8*)(sB + swz(wn * 32 + f * 16 + (lane & 15), kbyte));
#pragma unroll
      for (int fm = 0; fm < 4; ++fm)
#pragma unroll
        for (int fn = 0; fn < 2; ++fn)
          acc[fm][fn] = MFMA(av[fm], bv[fn], acc[fm][fn]);
    }
  }

  float* __restrict__ P = partial + (size_t)blockIdx.y * (256 * 512);
  const int r4 = (lane >> 4) * 4;
#pragma unroll
  for (int fn = 0; fn < 2; ++fn) {
    int col = n0 + wn * 32 + fn * 16 + (lane & 15);
#pragma unroll
    for (int fm = 0; fm < 4; ++fm) {
      int mb = wm * 64 + fm * 16 + r4;
#pragma unroll
      for (int j = 0; j < 4; ++j)
        P[(size_t)(mb + j) * 512 + col] = acc[fm][fn][j];
    }
  }
}

__global__ __launch_bounds__(256) void k_reduce(
    const float* __restrict__ partial,
    const float* __restrict__ ob,
    float* __restrict__ out)
{
  const int i = blockIdx.x * 256 + threadIdx.x;   // 131072 outputs
  float s = ob[i & 511];
#pragma unroll
  for (int ks = 0; ks < 32; ++ks) s += partial[(size_t)ks * 131072 + i];
  out[i] = s;
}

// ---------------------------------------------------------------------------
extern "C" void kernel_launch(void* const* d_in, const int* in_sizes, int n_in,
                              void* d_out, int out_size, void* d_ws, size_t ws_size,
                              hipStream_t stream) {
  const float* x         = (const float*)d_in[0];
  const float* k_w       = (const float*)d_in[1];
  const float* k_b       = (const float*)d_in[2];
  const float* q_w       = (const float*)d_in[3];
  const float* q_b       = (const float*)d_in[4];
  const float* v_w       = (const float*)d_in[5];
  const float* v_b       = (const float*)d_in[6];
  const float* attn_bias = (const float*)d_in[7];
  const float* ln_g      = (const float*)d_in[8];
  const float* ln_b      = (const float*)d_in[9];
  const float* out_w     = (const float*)d_in[10];
  const float* out_b     = (const float*)d_in[11];
  float* out = (float*)d_out;

  char* ws = (char*)d_ws;
  // buffers (bf16 unless noted); total 224 MiB. act aliases k_t (dead after
  // k_scores); partial (fp32, 16 MiB) aliases q_t (dead after k_scores).
  unsigned short* k_t = (unsigned short*)(ws);                // 64 MiB [B][H][S]
  unsigned short* q_t = (unsigned short*)(ws + 67108864);     // 64 MiB [B][H][S]
  unsigned short* v_o = (unsigned short*)(ws + 134217728);    // 64 MiB [B][S][H]
  unsigned short* w_t = (unsigned short*)(ws + 201326592);    // 32 MiB [B][H(g)][H(h)]
  unsigned short* act = k_t;                                  // [B][S][H]
  float* partial      = (float*)(ws + 67108864);              // [32][256][512]

  k_proj<<<dim3(6, 1024), dim3(512), 0, stream>>>(
      x, k_w, k_b, q_w, q_b, v_w, v_b, k_t, q_t, v_o);
  k_scores<<<dim3(4, 256), dim3(512), 0, stream>>>(k_t, q_t, w_t);
  k_pv<<<dim3(4, 256), dim3(512), 0, stream>>>(
      v_o, w_t, attn_bias, ln_g, ln_b, act);
  k_final<<<dim3(8, 32), dim3(512), 0, stream>>>(act, out_w, partial);
  k_reduce<<<dim3(512), dim3(256), 0, stream>>>(partial, out_b, out);
}

// Round 2
// 551.557 us; speedup vs baseline: 1.1071x; 1.1071x over previous
//
#include <hip/hip_runtime.h>
#include <hip/hip_bf16.h>
#include <math.h>

#define B_ 256
#define S_ 512
#define H_ 256
#define D_ 512

typedef __bf16 bf16;
typedef __bf16 bf16x8 __attribute__((ext_vector_type(8)));
typedef float  f32x4  __attribute__((ext_vector_type(4)));
typedef unsigned short u16x8 __attribute__((ext_vector_type(8)));
typedef unsigned short u16x4 __attribute__((ext_vector_type(4)));

#define MFMA(a, b, c) __builtin_amdgcn_mfma_f32_16x16x32_bf16((a), (b), (c), 0, 0, 0)

__device__ __forceinline__ int swz(int row, int kbyte) {
  return (row * 128 + kbyte) ^ ((row & 7) << 4);
}
__device__ __forceinline__ unsigned short bfbits(float f) {
  bf16 h = (bf16)f;
  union { bf16 b; unsigned short u; } c; c.b = h; return c.u;
}
__device__ __forceinline__ bf16x8 cvt8(const float* __restrict__ p) {
  f32x4 a = *(const f32x4*)p;
  f32x4 b = *(const f32x4*)(p + 4);
  bf16x8 r;
  r[0] = (bf16)a[0]; r[1] = (bf16)a[1]; r[2] = (bf16)a[2]; r[3] = (bf16)a[3];
  r[4] = (bf16)b[0]; r[5] = (bf16)b[1]; r[6] = (bf16)b[2]; r[7] = (bf16)b[3];
  return r;
}
// async global->LDS, 16B per lane. LDS dest = wave-uniform base + lane*16.
__device__ __forceinline__ void gload16(const unsigned short* g, unsigned char* l) {
  __builtin_amdgcn_global_load_lds(
      (const __attribute__((address_space(1))) unsigned int*)g,
      (__attribute__((address_space(3))) unsigned int*)l, 16, 0, 0);
}

// ---------------------------------------------------------------------------
// Conversion kernels (run once / per chunk). Numerics identical to staging
// cvt in round-1 kernel (same bf16 rounding point).
// ---------------------------------------------------------------------------
__global__ __launch_bounds__(256) void k_convw(
    const float* __restrict__ kw, const float* __restrict__ qw,
    const float* __restrict__ vw, unsigned short* __restrict__ wc)
{
  const int r = blockIdx.x;  // 0..767 combined rows: k, q, v
  const float* src = (r < 256) ? kw + (size_t)r * 512
                   : (r < 512) ? qw + (size_t)(r - 256) * 512
                               : vw + (size_t)(r - 512) * 512;
  const int c = threadIdx.x * 2;
  wc[(size_t)r * 512 + c]     = bfbits(src[c]);
  wc[(size_t)r * 512 + c + 1] = bfbits(src[c + 1]);
}

__global__ __launch_bounds__(256) void k_convx(
    const float* __restrict__ x, unsigned short* __restrict__ xb, int nchunk)
{
  for (int c = blockIdx.x * 256 + threadIdx.x; c < nchunk; c += gridDim.x * 256) {
    bf16x8 v = cvt8(x + (size_t)c * 8);
    *(bf16x8*)(xb + (size_t)c * 8) = v;
  }
}

// ---------------------------------------------------------------------------
// Kernel 1: QKV projection, m97 structure. xb: [nbat*512][512] bf16 chunk,
// wc: [768][512] bf16 (k rows 0..255, q 256..511, v 512..767).
// 128x128 tile, BK=64, 4 waves (2x2, 64x64 each), global_load_lds w16,
// linear LDS, XCD-chunked bijective swizzle (nwg % 8 == 0 always).
// ---------------------------------------------------------------------------
__global__ __launch_bounds__(256) void k_proj2(
    const unsigned short* __restrict__ xb,
    const unsigned short* __restrict__ wc,
    const float* __restrict__ kbi, const float* __restrict__ qbi,
    const float* __restrict__ vbi,
    unsigned short* __restrict__ k_t, unsigned short* __restrict__ q_t,
    unsigned short* __restrict__ v_o, int cstart, int nwg)
{
  __shared__ __align__(16) unsigned char sA[16384];  // 128 m x 64 k bf16
  __shared__ __align__(16) unsigned char sB[16384];  // 128 n x 64 k bf16

  const int o = blockIdx.x;
  const int cpx = nwg >> 3;
  const int a = (o & 7) * cpx + (o >> 3);            // bijective (nwg%8==0)
  const int mt = a / 6;
  const int nb = a - mt * 6;
  const int m0 = mt * 128;                           // local (chunk) row base
  const int n0 = nb * 128;                           // Wc row base
  const int region = nb >> 1;                        // 0=k 1=q 2=v
  const int h0 = (nb & 1) * 128;
  const float* __restrict__ Bi = (region == 0) ? kbi : (region == 1) ? qbi : vbi;

  const int tid = threadIdx.x;
  const int lane = tid & 63;
  const int wid = tid >> 6;
  const int wm = wid >> 1;                           // 0..1
  const int wn = wid & 1;                            // 0..1

  f32x4 acc[4][4];
#pragma unroll
  for (int i = 0; i < 4; ++i)
#pragma unroll
    for (int j = 0; j < 4; ++j) acc[i][j] = (f32x4){0.f, 0.f, 0.f, 0.f};

  const int lr = lane >> 3;                          // row-within-8
  const int lk = (lane & 7) << 3;                    // k elem offset (8-elt units)

  for (int kt = 0; kt < 8; ++kt) {
    if (kt) __syncthreads();
#pragma unroll
    for (int i = 0; i < 4; ++i) {
      const int chunk = wid * 4 + i;                 // 0..15, 8 rows each
      const int row = chunk * 8 + lr;
      gload16(xb + (size_t)(m0 + row) * 512 + kt * 64 + lk, sA + chunk * 1024);
      gload16(wc + (size_t)(n0 + row) * 512 + kt * 64 + lk, sB + chunk * 1024);
    }
    __syncthreads();
#pragma unroll
    for (int ks = 0; ks < 2; ++ks) {
      const int kb2 = ks * 64 + ((lane >> 4) << 4);
      bf16x8 av[4], bv[4];
#pragma unroll
      for (int f = 0; f < 4; ++f)
        av[f] = *(const bf16x8*)(sA + (wm * 64 + f * 16 + (lane & 15)) * 128 + kb2);
#pragma unroll
      for (int f = 0; f < 4; ++f)
        bv[f] = *(const bf16x8*)(sB + (wn * 64 + f * 16 + (lane & 15)) * 128 + kb2);
#pragma unroll
      for (int fm = 0; fm < 4; ++fm)
#pragma unroll
        for (int fn = 0; fn < 4; ++fn)
          acc[fm][fn] = MFMA(av[fm], bv[fn], acc[fm][fn]);
    }
  }

  const int m0g = cstart * 512 + m0;
  const int b = m0g >> 9;
  const int sbase = m0g & 511;
  const int r4 = (lane >> 4) * 4;
#pragma unroll
  for (int fn = 0; fn < 4; ++fn) {
    const int hcol = h0 + wn * 64 + fn * 16 + (lane & 15);
    const float bias = Bi[hcol];
#pragma unroll
    for (int fm = 0; fm < 4; ++fm) {
      const int s = sbase + wm * 64 + fm * 16 + r4;
      if (region < 2) {
        unsigned short* dst = ((region == 0) ? k_t : q_t) +
                              (size_t)b * (H_ * S_) + (size_t)hcol * S_ + s;
        u16x4 ov;
#pragma unroll
        for (int j = 0; j < 4; ++j) ov[j] = bfbits(acc[fm][fn][j] + bias);
        *(u16x4*)dst = ov;
      } else {
#pragma unroll
        for (int j = 0; j < 4; ++j)
          v_o[(size_t)b * (S_ * H_) + (size_t)(s + j) * H_ + hcol] =
              bfbits(acc[fm][fn][j] + bias);
      }
    }
  }
}

// ---------------------------------------------------------------------------
// Kernel 2: scores + column softmax (unchanged from round 1).
// ---------------------------------------------------------------------------
__global__ __launch_bounds__(512) void k_scores(
    const unsigned short* __restrict__ k_t,
    const unsigned short* __restrict__ q_t,
    unsigned short* __restrict__ w_t)
{
  __shared__ __align__(16) unsigned char sA[256 * 128];
  __shared__ __align__(16) unsigned char sB[64 * 128];
  __shared__ float red[4][64];

  const int tid = threadIdx.x;
  const int lane = tid & 63;
  const int wid = tid >> 6;
  const int wm = wid >> 1;
  const int wn = wid & 1;
  const int b = blockIdx.y;
  const int g0 = blockIdx.x * 64;

  const unsigned short* __restrict__ Ab = k_t + (size_t)b * (H_ * S_);
  const unsigned short* __restrict__ Bb = q_t + (size_t)b * (H_ * S_) + (size_t)g0 * S_;

  f32x4 acc[4][2];
#pragma unroll
  for (int i = 0; i < 4; ++i)
#pragma unroll
    for (int j = 0; j < 2; ++j) acc[i][j] = (f32x4){0.f, 0.f, 0.f, 0.f};

  for (int kt = 0; kt < 8; ++kt) {
    __syncthreads();
#pragma unroll
    for (int i = 0; i < 4; ++i) {
      int c = tid + i * 512;
      int row = c >> 3, kc = (c & 7) * 8;
      *(u16x8*)(sA + swz(row, kc * 2)) =
          *(const u16x8*)(Ab + (size_t)row * S_ + kt * 64 + kc);
    }
    {
      int row = tid >> 3, kc = (tid & 7) * 8;
      *(u16x8*)(sB + swz(row, kc * 2)) =
          *(const u16x8*)(Bb + (size_t)row * S_ + kt * 64 + kc);
    }
    __syncthreads();
#pragma unroll
    for (int ks = 0; ks < 2; ++ks) {
      const int kbyte = ks * 64 + (lane >> 4) * 16;
      bf16x8 av[4], bv[2];
#pragma unroll
      for (int f = 0; f < 4; ++f)
        av[f] = *(const bf16x8*)(sA + swz(wm * 64 + f * 16 + (lane & 15), kbyte));
#pragma unroll
      for (int f = 0; f < 2; ++f)
        bv[f] = *(const bf16x8*)(sB + swz(wn * 32 + f * 16 + (lane & 15), kbyte));
#pragma unroll
      for (int fm = 0; fm < 4; ++fm)
#pragma unroll
        for (int fn = 0; fn < 2; ++fn)
          acc[fm][fn] = MFMA(av[fm], bv[fn], acc[fm][fn]);
    }
  }

#pragma unroll
  for (int fm = 0; fm < 4; ++fm)
#pragma unroll
    for (int fn = 0; fn < 2; ++fn)
#pragma unroll
      for (int j = 0; j < 4; ++j) acc[fm][fn][j] *= 0.0625f;

  float cmax[2] = {-3.0e38f, -3.0e38f};
#pragma unroll
  for (int fm = 0; fm < 4; ++fm)
#pragma unroll
    for (int fn = 0; fn < 2; ++fn)
#pragma unroll
      for (int j = 0; j < 4; ++j) cmax[fn] = fmaxf(cmax[fn], acc[fm][fn][j]);
  cmax[0] = fmaxf(cmax[0], __shfl_xor(cmax[0], 16));
  cmax[1] = fmaxf(cmax[1], __shfl_xor(cmax[1], 16));
  cmax[0] = fmaxf(cmax[0], __shfl_xor(cmax[0], 32));
  cmax[1] = fmaxf(cmax[1], __shfl_xor(cmax[1], 32));
  if (lane < 16) {
    red[wm][wn * 32 + lane] = cmax[0];
    red[wm][wn * 32 + 16 + lane] = cmax[1];
  }
  __syncthreads();
  float gmax[2];
#pragma unroll
  for (int fn = 0; fn < 2; ++fn) {
    int c = wn * 32 + fn * 16 + (lane & 15);
    gmax[fn] = fmaxf(fmaxf(red[0][c], red[1][c]), fmaxf(red[2][c], red[3][c]));
  }
  __syncthreads();
  float csum[2] = {0.f, 0.f};
#pragma unroll
  for (int fm = 0; fm < 4; ++fm)
#pragma unroll
    for (int fn = 0; fn < 2; ++fn)
#pragma unroll
      for (int j = 0; j < 4; ++j) {
        float p = __expf(acc[fm][fn][j] - gmax[fn]);
        acc[fm][fn][j] = p;
        csum[fn] += p;
      }
  csum[0] += __shfl_xor(csum[0], 16);
  csum[1] += __shfl_xor(csum[1], 16);
  csum[0] += __shfl_xor(csum[0], 32);
  csum[1] += __shfl_xor(csum[1], 32);
  if (lane < 16) {
    red[wm][wn * 32 + lane] = csum[0];
    red[wm][wn * 32 + 16 + lane] = csum[1];
  }
  __syncthreads();
  const int r4 = (lane >> 4) * 4;
#pragma unroll
  for (int fn = 0; fn < 2; ++fn) {
    int c = wn * 32 + fn * 16 + (lane & 15);
    float ginv = 1.0f / (red[0][c] + red[1][c] + red[2][c] + red[3][c]);
    int g = g0 + c;
#pragma unroll
    for (int fm = 0; fm < 4; ++fm) {
      int h = wm * 64 + fm * 16 + r4;
      u16x4 ov;
#pragma unroll
      for (int j = 0; j < 4; ++j) ov[j] = bfbits(acc[fm][fn][j] * ginv);
      *(u16x4*)(w_t + (size_t)b * (H_ * H_) + (size_t)g * H_ + h) = ov;
    }
  }
}

// ---------------------------------------------------------------------------
// Kernel 3: PV + bias + LayerNorm + GELU (unchanged from round 1).
// ---------------------------------------------------------------------------
__global__ __launch_bounds__(512) void k_pv(
    const unsigned short* __restrict__ v_o,
    const unsigned short* __restrict__ w_t,
    const float* __restrict__ attn_bias,
    const float* __restrict__ lng,
    const float* __restrict__ lnb,
    unsigned short* __restrict__ act)
{
  __shared__ __align__(16) unsigned char sA[128 * 128];
  __shared__ __align__(16) unsigned char sB[256 * 128];
  __shared__ float lbuf[2][4][128];

  const int tid = threadIdx.x;
  const int lane = tid & 63;
  const int wid = tid >> 6;
  const int wm = wid >> 2;
  const int wn = wid & 3;
  const int b = blockIdx.y;
  const int s0 = blockIdx.x * 128;

  const unsigned short* __restrict__ Ab = v_o + (size_t)b * (S_ * H_) + (size_t)s0 * H_;
  const unsigned short* __restrict__ Bb = w_t + (size_t)b * (H_ * H_);

  f32x4 acc[4][4];
#pragma unroll
  for (int i = 0; i < 4; ++i)
#pragma unroll
    for (int j = 0; j < 4; ++j) acc[i][j] = (f32x4){0.f, 0.f, 0.f, 0.f};

  for (int kt = 0; kt < 4; ++kt) {
    __syncthreads();
#pragma unroll
    for (int i = 0; i < 2; ++i) {
      int c = tid + i * 512;
      int row = c >> 3, kc = (c & 7) * 8;
      *(u16x8*)(sA + swz(row, kc * 2)) =
          *(const u16x8*)(Ab + (size_t)row * H_ + kt * 64 + kc);
    }
#pragma unroll
    for (int i = 0; i < 4; ++i) {
      int c = tid + i * 512;
      int row = c >> 3, kc = (c & 7) * 8;
      *(u16x8*)(sB + swz(row, kc * 2)) =
          *(const u16x8*)(Bb + (size_t)row * H_ + kt * 64 + kc);
    }
    __syncthreads();
#pragma unroll
    for (int ks = 0; ks < 2; ++ks) {
      const int kbyte = ks * 64 + (lane >> 4) * 16;
      bf16x8 av[4], bv[4];
#pragma unroll
      for (int f = 0; f < 4; ++f)
        av[f] = *(const bf16x8*)(sA + swz(wm * 64 + f * 16 + (lane & 15), kbyte));
#pragma unroll
      for (int f = 0; f < 4; ++f)
        bv[f] = *(const bf16x8*)(sB + swz(wn * 64 + f * 16 + (lane & 15), kbyte));
#pragma unroll
      for (int fm = 0; fm < 4; ++fm)
#pragma unroll
        for (int fn = 0; fn < 4; ++fn)
          acc[fm][fn] = MFMA(av[fm], bv[fn], acc[fm][fn]);
    }
  }

  const int r4 = (lane >> 4) * 4;
  float lg[4], lb[4];
#pragma unroll
  for (int fn = 0; fn < 4; ++fn) {
    int g = wn * 64 + fn * 16 + (lane & 15);
    lg[fn] = lng[g];
    lb[fn] = lnb[g];
  }
#pragma unroll
  for (int fm = 0; fm < 4; ++fm) {
#pragma unroll
    for (int j = 0; j < 4; ++j) {
      const int rloc = wm * 64 + fm * 16 + r4 + j;
      const int sl = s0 + rloc;
      float ps = 0.f, psq = 0.f;
#pragma unroll
      for (int fn = 0; fn < 4; ++fn) {
        int g = wn * 64 + fn * 16 + (lane & 15);
        float vv = acc[fm][fn][j] + attn_bias[(size_t)sl * H_ + g];
        acc[fm][fn][j] = vv;
        ps += vv;
        psq += vv * vv;
      }
      ps += __shfl_xor(ps, 1);  psq += __shfl_xor(psq, 1);
      ps += __shfl_xor(ps, 2);  psq += __shfl_xor(psq, 2);
      ps += __shfl_xor(ps, 4);  psq += __shfl_xor(psq, 4);
      ps += __shfl_xor(ps, 8);  psq += __shfl_xor(psq, 8);
      if ((lane & 15) == 0) { lbuf[0][wn][rloc] = ps; lbuf[1][wn][rloc] = psq; }
    }
  }
  __syncthreads();
#pragma unroll
  for (int fm = 0; fm < 4; ++fm) {
#pragma unroll
    for (int j = 0; j < 4; ++j) {
      const int rloc = wm * 64 + fm * 16 + r4 + j;
      float sum = lbuf[0][0][rloc] + lbuf[0][1][rloc] + lbuf[0][2][rloc] + lbuf[0][3][rloc];
      float sq  = lbuf[1][0][rloc] + lbuf[1][1][rloc] + lbuf[1][2][rloc] + lbuf[1][3][rloc];
      float mu = sum * (1.f / H_);
      float var = sq * (1.f / H_) - mu * mu;
      float rstd = rsqrtf(var + 1e-5f);
      const int sl = s0 + rloc;
#pragma unroll
      for (int fn = 0; fn < 4; ++fn) {
        int g = wn * 64 + fn * 16 + (lane & 15);
        float xv = (acc[fm][fn][j] - mu) * rstd * lg[fn] + lb[fn];
        float y = 0.5f * xv * (1.f + erff(xv * 0.70710678118654752f));
        act[(size_t)b * (S_ * H_) + (size_t)sl * H_ + g] = bfbits(y);
      }
    }
  }
}

// ---------------------------------------------------------------------------
// Kernel 4: final GEMM, split-K (unchanged from round 1).
// ---------------------------------------------------------------------------
__global__ __launch_bounds__(512) void k_final(
    const unsigned short* __restrict__ act,
    const float* __restrict__ ow,
    float* __restrict__ partial)
{
  __shared__ __align__(16) unsigned char sA[256 * 128];
  __shared__ __align__(16) unsigned char sB[64 * 128];

  const int tid = threadIdx.x;
  const int lane = tid & 63;
  const int wid = tid >> 6;
  const int wm = wid >> 1;
  const int wn = wid & 1;
  const int n0 = blockIdx.x * 64;
  const size_t k0 = (size_t)blockIdx.y * 4096;

  f32x4 acc[4][2];
#pragma unroll
  for (int i = 0; i < 4; ++i)
#pragma unroll
    for (int j = 0; j < 2; ++j) acc[i][j] = (f32x4){0.f, 0.f, 0.f, 0.f};

  for (int kt = 0; kt < 64; ++kt) {
    const size_t kb = k0 + kt * 64;
    __syncthreads();
#pragma unroll
    for (int i = 0; i < 4; ++i) {
      int c = tid + i * 512;
      int row = c >> 3, kc = (c & 7) * 8;
      *(u16x8*)(sA + swz(row, kc * 2)) =
          *(const u16x8*)(act + (size_t)row * 131072 + kb + kc);
    }
    {
      int row = tid >> 3, kc = (tid & 7) * 8;
      *(bf16x8*)(sB + swz(row, kc * 2)) =
          cvt8(ow + (size_t)(n0 + row) * 131072 + kb + kc);
    }
    __syncthreads();
#pragma unroll
    for (int ks = 0; ks < 2; ++ks) {
      const int kbyte = ks * 64 + (lane >> 4) * 16;
      bf16x8 av[4], bv[2];
#pragma unroll
      for (int f = 0; f < 4; ++f)
        av[f] = *(const bf16x8*)(sA + swz(wm * 64 + f * 16 + (lane & 15), kbyte));
#pragma unroll
      for (int f = 0; f < 2; ++f)
        bv[f] = *(const bf16x8*)(sB + swz(wn * 32 + f * 16 + (lane & 15), kbyte));
#pragma unroll
      for (int fm = 0; fm < 4; ++fm)
#pragma unroll
        for (int fn = 0; fn < 2; ++fn)
          acc[fm][fn] = MFMA(av[fm], bv[fn], acc[fm][fn]);
    }
  }

  float* __restrict__ P = partial + (size_t)blockIdx.y * (256 * 512);
  const int r4 = (lane >> 4) * 4;
#pragma unroll
  for (int fn = 0; fn < 2; ++fn) {
    int col = n0 + wn * 32 + fn * 16 + (lane & 15);
#pragma unroll
    for (int fm = 0; fm < 4; ++fm) {
      int mb = wm * 64 + fm * 16 + r4;
#pragma unroll
      for (int j = 0; j < 4; ++j)
        P[(size_t)(mb + j) * 512 + col] = acc[fm][fn][j];
    }
  }
}

__global__ __launch_bounds__(256) void k_reduce(
    const float* __restrict__ partial,
    const float* __restrict__ ob,
    float* __restrict__ out)
{
  const int i4 = blockIdx.x * 256 + threadIdx.x;   // 32768 float4 groups
  f32x4 s = *(const f32x4*)(ob + ((i4 & 127) << 2));
#pragma unroll
  for (int ks = 0; ks < 32; ++ks)
    s += *(const f32x4*)(partial + (size_t)ks * 131072 + (size_t)i4 * 4);
  *(f32x4*)(out + (size_t)i4 * 4) = s;
}

// ---------------------------------------------------------------------------
extern "C" void kernel_launch(void* const* d_in, const int* in_sizes, int n_in,
                              void* d_out, int out_size, void* d_ws, size_t ws_size,
                              hipStream_t stream) {
  const float* x         = (const float*)d_in[0];
  const float* k_w       = (const float*)d_in[1];
  const float* k_b       = (const float*)d_in[2];
  const float* q_w       = (const float*)d_in[3];
  const float* q_b       = (const float*)d_in[4];
  const float* v_w       = (const float*)d_in[5];
  const float* v_b       = (const float*)d_in[6];
  const float* attn_bias = (const float*)d_in[7];
  const float* ln_g      = (const float*)d_in[8];
  const float* ln_b      = (const float*)d_in[9];
  const float* out_w     = (const float*)d_in[10];
  const float* out_b     = (const float*)d_in[11];
  float* out = (float*)d_out;

  char* ws = (char*)d_ws;
  // Layout (224 MiB total, matching round-1's proven footprint):
  //   [0,64M)    k_t  [B][H][S] bf16            (later aliased by act)
  //   [64,128M)  q_t  [B][H][S] bf16            (later aliased by partial)
  //   [128,192M) v_o  [B][S][H] bf16
  //   [192,224M) slot: during proj = wc (768K) + xb chunk (28 MiB);
  //              after proj = w_t [B][g][h] bf16 (32 MiB)
  unsigned short* k_t = (unsigned short*)(ws);
  unsigned short* q_t = (unsigned short*)(ws + 67108864);
  unsigned short* v_o = (unsigned short*)(ws + 134217728);
  unsigned short* wc  = (unsigned short*)(ws + 201326592);
  unsigned short* xb  = (unsigned short*)(ws + 201326592 + 786432);
  unsigned short* w_t = (unsigned short*)(ws + 201326592);
  unsigned short* act = k_t;
  float* partial      = (float*)(ws + 67108864);

  k_convw<<<dim3(768), dim3(256), 0, stream>>>(k_w, q_w, v_w, wc);

  // x -> bf16 in 56-batch chunks (28 MiB), proj per chunk.
  const int starts[5] = {0, 56, 112, 168, 224};
  const int nbats[5]  = {56, 56, 56, 56, 32};
  for (int r = 0; r < 5; ++r) {
    const int nbat = nbats[r];
    k_convx<<<dim3(1024), dim3(256), 0, stream>>>(
        x + (size_t)starts[r] * 262144, xb, nbat * 32768);
    const int nwg = nbat * 24;  // (nbat*4 m-tiles) x 6 n-tiles, %8==0
    k_proj2<<<dim3(nwg), dim3(256), 0, stream>>>(
        xb, wc, k_b, q_b, v_b, k_t, q_t, v_o, starts[r], nwg);
  }

  k_scores<<<dim3(4, 256), dim3(512), 0, stream>>>(k_t, q_t, w_t);
  k_pv<<<dim3(4, 256), dim3(512), 0, stream>>>(
      v_o, w_t, attn_bias, ln_g, ln_b, act);
  k_final<<<dim3(8, 32), dim3(512), 0, stream>>>(act, out_w, partial);
  k_reduce<<<dim3(128), dim3(256), 0, stream>>>(partial, out_b, out);
}

// Round 3
// 517.840 us; speedup vs baseline: 1.1792x; 1.0651x over previous
//
#include <hip/hip_runtime.h>
#include <hip/hip_bf16.h>
#include <math.h>

#define B_ 256
#define S_ 512
#define H_ 256
#define D_ 512

typedef __bf16 bf16;
typedef __bf16 bf16x8 __attribute__((ext_vector_type(8)));
typedef float  f32x4  __attribute__((ext_vector_type(4)));
typedef unsigned short u16x8 __attribute__((ext_vector_type(8)));
typedef unsigned short u16x4 __attribute__((ext_vector_type(4)));

#define MFMA(a, b, c) __builtin_amdgcn_mfma_f32_16x16x32_bf16((a), (b), (c), 0, 0, 0)

// row stride 128B tiles (64 k bf16): XOR-swizzle, same involution on write+read.
__device__ __forceinline__ int swz(int row, int kbyte) {
  return (row * 128 + kbyte) ^ ((row & 7) << 4);
}
// row stride 512B tiles (256 h bf16) for the in-LDS P matrix.
__device__ __forceinline__ int pswz(int row, int kbyte) {
  return (row * 512 + kbyte) ^ ((row & 7) << 4);
}
__device__ __forceinline__ unsigned short bfbits(float f) {
  bf16 h = (bf16)f;
  union { bf16 b; unsigned short u; } c; c.b = h; return c.u;
}
__device__ __forceinline__ bf16x8 cvt8(const float* __restrict__ p) {
  f32x4 a = *(const f32x4*)p;
  f32x4 b = *(const f32x4*)(p + 4);
  bf16x8 r;
  r[0] = (bf16)a[0]; r[1] = (bf16)a[1]; r[2] = (bf16)a[2]; r[3] = (bf16)a[3];
  r[4] = (bf16)b[0]; r[5] = (bf16)b[1]; r[6] = (bf16)b[2]; r[7] = (bf16)b[3];
  return r;
}
__device__ __forceinline__ void gload16(const unsigned short* g, unsigned char* l) {
  __builtin_amdgcn_global_load_lds(
      (const __attribute__((address_space(1))) unsigned int*)g,
      (__attribute__((address_space(3))) unsigned int*)l, 16, 0, 0);
}

// ---------------------------------------------------------------------------
// Conversion kernels (unchanged).
// ---------------------------------------------------------------------------
__global__ __launch_bounds__(256) void k_convw(
    const float* __restrict__ kw, const float* __restrict__ qw,
    const float* __restrict__ vw, unsigned short* __restrict__ wc)
{
  const int r = blockIdx.x;
  const float* src = (r < 256) ? kw + (size_t)r * 512
                   : (r < 512) ? qw + (size_t)(r - 256) * 512
                               : vw + (size_t)(r - 512) * 512;
  const int c = threadIdx.x * 2;
  wc[(size_t)r * 512 + c]     = bfbits(src[c]);
  wc[(size_t)r * 512 + c + 1] = bfbits(src[c + 1]);
}

__global__ __launch_bounds__(256) void k_convx(
    const float* __restrict__ x, unsigned short* __restrict__ xb, int nchunk)
{
  for (int c = blockIdx.x * 256 + threadIdx.x; c < nchunk; c += gridDim.x * 256) {
    bf16x8 v = cvt8(x + (size_t)c * 8);
    *(bf16x8*)(xb + (size_t)c * 8) = v;
  }
}

// ---------------------------------------------------------------------------
// Kernel 1: QKV projection (unchanged from round 2).
// ---------------------------------------------------------------------------
__global__ __launch_bounds__(256) void k_proj2(
    const unsigned short* __restrict__ xb,
    const unsigned short* __restrict__ wc,
    const float* __restrict__ kbi, const float* __restrict__ qbi,
    const float* __restrict__ vbi,
    unsigned short* __restrict__ k_t, unsigned short* __restrict__ q_t,
    unsigned short* __restrict__ v_o, int cstart, int nwg)
{
  __shared__ __align__(16) unsigned char sA[16384];
  __shared__ __align__(16) unsigned char sB[16384];

  const int o = blockIdx.x;
  const int cpx = nwg >> 3;
  const int a = (o & 7) * cpx + (o >> 3);
  const int mt = a / 6;
  const int nb = a - mt * 6;
  const int m0 = mt * 128;
  const int n0 = nb * 128;
  const int region = nb >> 1;
  const int h0 = (nb & 1) * 128;
  const float* __restrict__ Bi = (region == 0) ? kbi : (region == 1) ? qbi : vbi;

  const int tid = threadIdx.x;
  const int lane = tid & 63;
  const int wid = tid >> 6;
  const int wm = wid >> 1;
  const int wn = wid & 1;

  f32x4 acc[4][4];
#pragma unroll
  for (int i = 0; i < 4; ++i)
#pragma unroll
    for (int j = 0; j < 4; ++j) acc[i][j] = (f32x4){0.f, 0.f, 0.f, 0.f};

  const int lr = lane >> 3;
  const int lk = (lane & 7) << 3;

  for (int kt = 0; kt < 8; ++kt) {
    if (kt) __syncthreads();
#pragma unroll
    for (int i = 0; i < 4; ++i) {
      const int chunk = wid * 4 + i;
      const int row = chunk * 8 + lr;
      gload16(xb + (size_t)(m0 + row) * 512 + kt * 64 + lk, sA + chunk * 1024);
      gload16(wc + (size_t)(n0 + row) * 512 + kt * 64 + lk, sB + chunk * 1024);
    }
    __syncthreads();
#pragma unroll
    for (int ks = 0; ks < 2; ++ks) {
      const int kb2 = ks * 64 + ((lane >> 4) << 4);
      bf16x8 av[4], bv[4];
#pragma unroll
      for (int f = 0; f < 4; ++f)
        av[f] = *(const bf16x8*)(sA + (wm * 64 + f * 16 + (lane & 15)) * 128 + kb2);
#pragma unroll
      for (int f = 0; f < 4; ++f)
        bv[f] = *(const bf16x8*)(sB + (wn * 64 + f * 16 + (lane & 15)) * 128 + kb2);
#pragma unroll
      for (int fm = 0; fm < 4; ++fm)
#pragma unroll
        for (int fn = 0; fn < 4; ++fn)
          acc[fm][fn] = MFMA(av[fm], bv[fn], acc[fm][fn]);
    }
  }

  const int m0g = cstart * 512 + m0;
  const int b = m0g >> 9;
  const int sbase = m0g & 511;
  const int r4 = (lane >> 4) * 4;
#pragma unroll
  for (int fn = 0; fn < 4; ++fn) {
    const int hcol = h0 + wn * 64 + fn * 16 + (lane & 15);
    const float bias = Bi[hcol];
#pragma unroll
    for (int fm = 0; fm < 4; ++fm) {
      const int s = sbase + wm * 64 + fm * 16 + r4;
      if (region < 2) {
        unsigned short* dst = ((region == 0) ? k_t : q_t) +
                              (size_t)b * (H_ * S_) + (size_t)hcol * S_ + s;
        u16x4 ov;
#pragma unroll
        for (int j = 0; j < 4; ++j) ov[j] = bfbits(acc[fm][fn][j] + bias);
        *(u16x4*)dst = ov;
      } else {
#pragma unroll
        for (int j = 0; j < 4; ++j)
          v_o[(size_t)b * (S_ * H_) + (size_t)(s + j) * H_ + hcol] =
              bfbits(acc[fm][fn][j] + bias);
      }
    }
  }
}

// ---------------------------------------------------------------------------
// Kernel 2 (NEW): fused scores + column-softmax + PV + bias + LN + GELU.
// One block (512 thr, 8 waves) per batch. P (256h x 256g bf16) lives in LDS.
// Phase 1: S = k_t[b] (256h x 512s) . q_t[b]^T, wave grid 2h x 4g,
//          wave tile 128h x 64g (acc1[8][4]).
// Softmax over h (column), then P[g][h] = w, XOR-swizzled, in sP.
// Phase 2: out[s,g] = sum_h v[s,h] P[g,h]; A-frags straight from global
//          (16-lane groups read 64B-contiguous), B-frags from sP.
// Epilogue per 128-s m-step: +attn_bias, LN over g, erf-GELU, store bf16.
// ---------------------------------------------------------------------------
__global__ __launch_bounds__(512, 2) void k_attn(
    const unsigned short* __restrict__ k_t,
    const unsigned short* __restrict__ q_t,
    const unsigned short* __restrict__ v_o,
    const float* __restrict__ attn_bias,
    const float* __restrict__ lng, const float* __restrict__ lnb,
    unsigned short* __restrict__ act)
{
  __shared__ __align__(16) unsigned char sP[131072];  // P[256g][256h] bf16
  __shared__ float lbuf[2][4][128];                   // LN partials

  const int tid = threadIdx.x;
  const int lane = tid & 63;
  const int wid = tid >> 6;
  const int b = blockIdx.x;
  const int l15 = lane & 15;
  const int l16 = lane >> 4;          // 0..3
  const int r4 = l16 * 4;

  const unsigned short* __restrict__ Kb = k_t + (size_t)b * (H_ * S_);
  const unsigned short* __restrict__ Qb = q_t + (size_t)b * (H_ * S_);
  const unsigned short* __restrict__ Vb = v_o + (size_t)b * (S_ * H_);

  // phase-1 aliases inside the (not yet written) P region
  unsigned char* sK = sP;                    // 32KB: 256h x 64s
  unsigned char* sQ = sP + 32768;            // 32KB: 256g x 64s
  float* redm = (float*)(sP + 65536);        // [2][256]
  float* reds = (float*)(sP + 67584);        // [2][256]

  const int wh = wid >> 2;                   // 0..1 (h half / s half)
  const int wg = wid & 3;                    // 0..3 (g quarter)

  f32x4 acc1[8][4];
#pragma unroll
  for (int i = 0; i < 8; ++i)
#pragma unroll
    for (int j = 0; j < 4; ++j) acc1[i][j] = (f32x4){0.f, 0.f, 0.f, 0.f};

  // ---- Phase 1: S = K . Q^T over K=512 (8 staged steps of 64) ----
  for (int kt = 0; kt < 8; ++kt) {
    __syncthreads();
#pragma unroll
    for (int i = 0; i < 4; ++i) {
      int c = tid + i * 512;                 // 2048 16B chunks each
      int row = c >> 3, kc = (c & 7) * 8;
      *(u16x8*)(sK + swz(row, kc * 2)) =
          *(const u16x8*)(Kb + (size_t)row * S_ + kt * 64 + kc);
      *(u16x8*)(sQ + swz(row, kc * 2)) =
          *(const u16x8*)(Qb + (size_t)row * S_ + kt * 64 + kc);
    }
    __syncthreads();
#pragma unroll
    for (int ks = 0; ks < 2; ++ks) {
      const int kbyte = ks * 64 + l16 * 16;
      bf16x8 av[8], bv[4];
#pragma unroll
      for (int f = 0; f < 8; ++f)
        av[f] = *(const bf16x8*)(sK + swz(wh * 128 + f * 16 + l15, kbyte));
#pragma unroll
      for (int f = 0; f < 4; ++f)
        bv[f] = *(const bf16x8*)(sQ + swz(wg * 64 + f * 16 + l15, kbyte));
#pragma unroll
      for (int fm = 0; fm < 8; ++fm)
#pragma unroll
        for (int fn = 0; fn < 4; ++fn)
          acc1[fm][fn] = MFMA(av[fm], bv[fn], acc1[fm][fn]);
    }
  }

  // ---- scale + column softmax over h (256 = 8 fm-frags x 4 rows x 2 wh) ----
#pragma unroll
  for (int fm = 0; fm < 8; ++fm)
#pragma unroll
    for (int fn = 0; fn < 4; ++fn)
#pragma unroll
      for (int j = 0; j < 4; ++j) acc1[fm][fn][j] *= 0.0625f;

  float cmax[4] = {-3.0e38f, -3.0e38f, -3.0e38f, -3.0e38f};
#pragma unroll
  for (int fm = 0; fm < 8; ++fm)
#pragma unroll
    for (int fn = 0; fn < 4; ++fn)
#pragma unroll
      for (int j = 0; j < 4; ++j) cmax[fn] = fmaxf(cmax[fn], acc1[fm][fn][j]);
#pragma unroll
  for (int fn = 0; fn < 4; ++fn) {
    cmax[fn] = fmaxf(cmax[fn], __shfl_xor(cmax[fn], 16));
    cmax[fn] = fmaxf(cmax[fn], __shfl_xor(cmax[fn], 32));
  }
  if (lane < 16) {
#pragma unroll
    for (int fn = 0; fn < 4; ++fn)
      redm[wh * 256 + wg * 64 + fn * 16 + lane] = cmax[fn];
  }
  __syncthreads();
  float gmax[4];
#pragma unroll
  for (int fn = 0; fn < 4; ++fn) {
    int c = wg * 64 + fn * 16 + l15;
    gmax[fn] = fmaxf(redm[c], redm[256 + c]);
  }
  float csum[4] = {0.f, 0.f, 0.f, 0.f};
#pragma unroll
  for (int fm = 0; fm < 8; ++fm)
#pragma unroll
    for (int fn = 0; fn < 4; ++fn)
#pragma unroll
      for (int j = 0; j < 4; ++j) {
        float p = __expf(acc1[fm][fn][j] - gmax[fn]);
        acc1[fm][fn][j] = p;
        csum[fn] += p;
      }
#pragma unroll
  for (int fn = 0; fn < 4; ++fn) {
    csum[fn] += __shfl_xor(csum[fn], 16);
    csum[fn] += __shfl_xor(csum[fn], 32);
  }
  if (lane < 16) {
#pragma unroll
    for (int fn = 0; fn < 4; ++fn)
      reds[wh * 256 + wg * 64 + fn * 16 + lane] = csum[fn];
  }
  __syncthreads();
  float ginv[4];
#pragma unroll
  for (int fn = 0; fn < 4; ++fn) {
    int c = wg * 64 + fn * 16 + l15;
    ginv[fn] = 1.0f / (reds[c] + reds[256 + c]);
  }
  __syncthreads();   // all red reads done before P overwrites the region

  // ---- write P[g][h] bf16 (swizzled) ----
#pragma unroll
  for (int fn = 0; fn < 4; ++fn) {
    const int g = wg * 64 + fn * 16 + l15;
#pragma unroll
    for (int fm = 0; fm < 8; ++fm) {
      const int h = wh * 128 + fm * 16 + r4;
      u16x4 pv;
#pragma unroll
      for (int j = 0; j < 4; ++j) pv[j] = bfbits(acc1[fm][fn][j] * ginv[fn]);
      *(u16x4*)(sP + pswz(g, h * 2)) = pv;
    }
  }
  __syncthreads();

  // ---- Phase 2: out = V . P^T, 4 m-steps of 128 s ----
  const float* __restrict__ bias = attn_bias;
  for (int ms = 0; ms < 4; ++ms) {
    const int s0 = ms * 128 + wh * 64;       // wave's s base
    f32x4 acc2[4][4];
#pragma unroll
    for (int i = 0; i < 4; ++i)
#pragma unroll
      for (int j = 0; j < 4; ++j) acc2[i][j] = (f32x4){0.f, 0.f, 0.f, 0.f};

#pragma unroll
    for (int kt = 0; kt < 4; ++kt) {         // h in blocks of 64
      bf16x8 av[4][2];
#pragma unroll
      for (int fm = 0; fm < 4; ++fm)
#pragma unroll
        for (int ks = 0; ks < 2; ++ks)
          av[fm][ks] = *(const bf16x8*)(
              Vb + (size_t)(s0 + fm * 16 + l15) * H_ + kt * 64 + ks * 32 + l16 * 8);
#pragma unroll
      for (int ks = 0; ks < 2; ++ks) {
        bf16x8 bv[4];
#pragma unroll
        for (int fn = 0; fn < 4; ++fn)
          bv[fn] = *(const bf16x8*)(
              sP + pswz(wg * 64 + fn * 16 + l15, kt * 128 + ks * 64 + l16 * 16));
#pragma unroll
        for (int fm = 0; fm < 4; ++fm)
#pragma unroll
          for (int fn = 0; fn < 4; ++fn)
            acc2[fm][fn] = MFMA(av[fm][ks], bv[fn], acc2[fm][fn]);
      }
    }

    // epilogue: +bias, LN over g (cross-wave via lbuf), GELU, store
    __syncthreads();                         // lbuf safe to rewrite
#pragma unroll
    for (int fm = 0; fm < 4; ++fm) {
#pragma unroll
      for (int j = 0; j < 4; ++j) {
        const int rloc = wh * 64 + fm * 16 + r4 + j;   // 0..127
        const int s = ms * 128 + rloc;
        float ps = 0.f, psq = 0.f;
#pragma unroll
        for (int fn = 0; fn < 4; ++fn) {
          int g = wg * 64 + fn * 16 + l15;
          float vv = acc2[fm][fn][j] + bias[(size_t)s * H_ + g];
          acc2[fm][fn][j] = vv;
          ps += vv; psq += vv * vv;
        }
        ps += __shfl_xor(ps, 1);  psq += __shfl_xor(psq, 1);
        ps += __shfl_xor(ps, 2);  psq += __shfl_xor(psq, 2);
        ps += __shfl_xor(ps, 4);  psq += __shfl_xor(psq, 4);
        ps += __shfl_xor(ps, 8);  psq += __shfl_xor(psq, 8);
        if (l15 == 0) { lbuf[0][wg][rloc] = ps; lbuf[1][wg][rloc] = psq; }
      }
    }
    __syncthreads();
#pragma unroll
    for (int fm = 0; fm < 4; ++fm) {
#pragma unroll
      for (int j = 0; j < 4; ++j) {
        const int rloc = wh * 64 + fm * 16 + r4 + j;
        const int s = ms * 128 + rloc;
        float sum = lbuf[0][0][rloc] + lbuf[0][1][rloc] + lbuf[0][2][rloc] + lbuf[0][3][rloc];
        float sq  = lbuf[1][0][rloc] + lbuf[1][1][rloc] + lbuf[1][2][rloc] + lbuf[1][3][rloc];
        float mu = sum * (1.f / H_);
        float var = sq * (1.f / H_) - mu * mu;
        float rstd = rsqrtf(var + 1e-5f);
#pragma unroll
        for (int fn = 0; fn < 4; ++fn) {
          int g = wg * 64 + fn * 16 + l15;
          float xv = (acc2[fm][fn][j] - mu) * rstd * lng[g] + lnb[g];
          float y = 0.5f * xv * (1.f + erff(xv * 0.70710678118654752f));
          act[(size_t)b * (S_ * H_) + (size_t)s * H_ + g] = bfbits(y);
        }
      }
    }
  }
}

// ---------------------------------------------------------------------------
// Kernel 3: final GEMM, split-K (unchanged).
// ---------------------------------------------------------------------------
__global__ __launch_bounds__(512) void k_final(
    const unsigned short* __restrict__ act,
    const float* __restrict__ ow,
    float* __restrict__ partial)
{
  __shared__ __align__(16) unsigned char sA[256 * 128];
  __shared__ __align__(16) unsigned char sB[64 * 128];

  const int tid = threadIdx.x;
  const int lane = tid & 63;
  const int wid = tid >> 6;
  const int wm = wid >> 1;
  const int wn = wid & 1;
  const int n0 = blockIdx.x * 64;
  const size_t k0 = (size_t)blockIdx.y * 4096;

  f32x4 acc[4][2];
#pragma unroll
  for (int i = 0; i < 4; ++i)
#pragma unroll
    for (int j = 0; j < 2; ++j) acc[i][j] = (f32x4){0.f, 0.f, 0.f, 0.f};

  for (int kt = 0; kt < 64; ++kt) {
    const size_t kb = k0 + kt * 64;
    __syncthreads();
#pragma unroll
    for (int i = 0; i < 4; ++i) {
      int c = tid + i * 512;
      int row = c >> 3, kc = (c & 7) * 8;
      *(u16x8*)(sA + swz(row, kc * 2)) =
          *(const u16x8*)(act + (size_t)row * 131072 + kb + kc);
    }
    {
      int row = tid >> 3, kc = (tid & 7) * 8;
      *(bf16x8*)(sB + swz(row, kc * 2)) =
          cvt8(ow + (size_t)(n0 + row) * 131072 + kb + kc);
    }
    __syncthreads();
#pragma unroll
    for (int ks = 0; ks < 2; ++ks) {
      const int kbyte = ks * 64 + (lane >> 4) * 16;
      bf16x8 av[4], bv[2];
#pragma unroll
      for (int f = 0; f < 4; ++f)
        av[f] = *(const bf16x8*)(sA + swz(wm * 64 + f * 16 + (lane & 15), kbyte));
#pragma unroll
      for (int f = 0; f < 2; ++f)
        bv[f] = *(const bf16x8*)(sB + swz(wn * 32 + f * 16 + (lane & 15), kbyte));
#pragma unroll
      for (int fm = 0; fm < 4; ++fm)
#pragma unroll
        for (int fn = 0; fn < 2; ++fn)
          acc[fm][fn] = MFMA(av[fm], bv[fn], acc[fm][fn]);
    }
  }

  float* __restrict__ P = partial + (size_t)blockIdx.y * (256 * 512);
  const int r4 = (lane >> 4) * 4;
#pragma unroll
  for (int fn = 0; fn < 2; ++fn) {
    int col = n0 + wn * 32 + fn * 16 + (lane & 15);
#pragma unroll
    for (int fm = 0; fm < 4; ++fm) {
      int mb = wm * 64 + fm * 16 + r4;
#pragma unroll
      for (int j = 0; j < 4; ++j)
        P[(size_t)(mb + j) * 512 + col] = acc[fm][fn][j];
    }
  }
}

__global__ __launch_bounds__(256) void k_reduce(
    const float* __restrict__ partial,
    const float* __restrict__ ob,
    float* __restrict__ out)
{
  const int i4 = blockIdx.x * 256 + threadIdx.x;
  f32x4 s = *(const f32x4*)(ob + ((i4 & 127) << 2));
#pragma unroll
  for (int ks = 0; ks < 32; ++ks)
    s += *(const f32x4*)(partial + (size_t)ks * 131072 + (size_t)i4 * 4);
  *(f32x4*)(out + (size_t)i4 * 4) = s;
}

// ---------------------------------------------------------------------------
extern "C" void kernel_launch(void* const* d_in, const int* in_sizes, int n_in,
                              void* d_out, int out_size, void* d_ws, size_t ws_size,
                              hipStream_t stream) {
  const float* x         = (const float*)d_in[0];
  const float* k_w       = (const float*)d_in[1];
  const float* k_b       = (const float*)d_in[2];
  const float* q_w       = (const float*)d_in[3];
  const float* q_b       = (const float*)d_in[4];
  const float* v_w       = (const float*)d_in[5];
  const float* v_b       = (const float*)d_in[6];
  const float* attn_bias = (const float*)d_in[7];
  const float* ln_g      = (const float*)d_in[8];
  const float* ln_b      = (const float*)d_in[9];
  const float* out_w     = (const float*)d_in[10];
  const float* out_b     = (const float*)d_in[11];
  float* out = (float*)d_out;

  char* ws = (char*)d_ws;
  // Layout:
  //   [0,64M)    k_t [B][H][S] bf16   (aliased by act after k_attn phase 1;
  //                                    alias is per-block safe: block b reads
  //                                    k_t[b] only in phase 1, writes act[b]
  //                                    only in phase 2, ordered by barriers)
  //   [64,128M)  q_t [B][H][S] bf16   (aliased by partial after k_attn)
  //   [128,192M) v_o [B][S][H] bf16
  //   [192,...)  wc (768K) + xb chunk (28 MiB) during proj
  unsigned short* k_t = (unsigned short*)(ws);
  unsigned short* q_t = (unsigned short*)(ws + 67108864);
  unsigned short* v_o = (unsigned short*)(ws + 134217728);
  unsigned short* wc  = (unsigned short*)(ws + 201326592);
  unsigned short* xb  = (unsigned short*)(ws + 201326592 + 786432);
  unsigned short* act = k_t;
  float* partial      = (float*)(ws + 67108864);

  k_convw<<<dim3(768), dim3(256), 0, stream>>>(k_w, q_w, v_w, wc);

  const int starts[5] = {0, 56, 112, 168, 224};
  const int nbats[5]  = {56, 56, 56, 56, 32};
  for (int r = 0; r < 5; ++r) {
    const int nbat = nbats[r];
    k_convx<<<dim3(1024), dim3(256), 0, stream>>>(
        x + (size_t)starts[r] * 262144, xb, nbat * 32768);
    const int nwg = nbat * 24;
    k_proj2<<<dim3(nwg), dim3(256), 0, stream>>>(
        xb, wc, k_b, q_b, v_b, k_t, q_t, v_o, starts[r], nwg);
  }

  k_attn<<<dim3(256), dim3(512), 0, stream>>>(
      k_t, q_t, v_o, attn_bias, ln_g, ln_b, act);

  k_final<<<dim3(8, 32), dim3(512), 0, stream>>>(act, out_w, partial);
  k_reduce<<<dim3(128), dim3(256), 0, stream>>>(partial, out_b, out);
}